// Round 7
// baseline (256.302 us; speedup 1.0000x reference)
//
#include <hip/hip_runtime.h>
#include <hip/hip_bf16.h>

// MultiHeadSelfAttention: B=2, S=2048, D=1024, H=16, HD=64
// d_out = out [2,2048,1024] fp32 ++ attn [2,16,2048,2048] fp32.
// bf16 MFMA 16x16x32, fp32 accum. global_load_lds(16B) staging, double-buffered
// single-barrier loops. V^T from the V-projection epilogue. Attention: 256-thread
// blocks (4 waves x 32 q-rows), 2-pass no-max softmax, exp2 folding (Q pre-scaled
// 0.125*log2e), pass-2 normalization folded into the MFMA C-init (lbias = -log2 l).

typedef __attribute__((ext_vector_type(8))) __bf16 bf16x8;
typedef __attribute__((ext_vector_type(8))) short short8;
typedef __attribute__((ext_vector_type(4))) float f32x4;
typedef __attribute__((ext_vector_type(4))) float float4v;
typedef __attribute__((ext_vector_type(4))) unsigned short ushort4v;
typedef __attribute__((ext_vector_type(8))) unsigned short ushort8v;

#define DEV static __device__ __forceinline__

DEV unsigned short f2bf(float f) {
  unsigned int u = __builtin_bit_cast(unsigned int, f);
  u += 0x7FFFu + ((u >> 16) & 1u);  // RNE
  return (unsigned short)(u >> 16);
}

DEV float exp2v(float x) {  // 2^x via compiler-managed intrinsic (hazard-safe)
#if __has_builtin(__builtin_amdgcn_exp2f)
  return __builtin_amdgcn_exp2f(x);
#else
  return exp2f(x);
#endif
}

DEV f32x4 mfma16(short8 a, short8 b, f32x4 c) {
  return __builtin_amdgcn_mfma_f32_16x16x32_bf16(
      __builtin_bit_cast(bf16x8, a), __builtin_bit_cast(bf16x8, b), c, 0, 0, 0);
}

DEV void gld16(const void* g, void* l) {
  __builtin_amdgcn_global_load_lds(
      (const __attribute__((address_space(1))) void*)g,
      (__attribute__((address_space(3))) void*)l, 16, 0, 0);
}

#define QSCALE 0.18033688011112042f  // 0.125 * log2(e)

// ---------------- fused fp32 -> bf16 bulk convert (x + 4 weights) ------------
__global__ __launch_bounds__(256) void cvt_all(
    const float* __restrict__ x, const float* __restrict__ wq,
    const float* __restrict__ wk, const float* __restrict__ wv,
    const float* __restrict__ wo, unsigned short* __restrict__ xb,
    unsigned short* __restrict__ wqb, unsigned short* __restrict__ wkb,
    unsigned short* __restrict__ wvb, unsigned short* __restrict__ wob) {
  const int bid = blockIdx.x;
  const float* s;
  unsigned short* d;
  int base;
  if (bid < 2048) {
    s = x; d = xb; base = bid * 2048;
  } else {
    const int j = bid - 2048, sel = j >> 9;
    s = sel == 0 ? wq : (sel == 1 ? wk : (sel == 2 ? wv : wo));
    d = sel == 0 ? wqb : (sel == 1 ? wkb : (sel == 2 ? wvb : wob));
    base = (j & 511) * 2048;
  }
  const int i = base + threadIdx.x * 8;
  float4v v0 = *(const float4v*)(s + i);
  float4v v1 = *(const float4v*)(s + i + 4);
  ushort8v o = {f2bf(v0[0]), f2bf(v0[1]), f2bf(v0[2]), f2bf(v0[3]),
                f2bf(v1[0]), f2bf(v1[1]), f2bf(v1[2]), f2bf(v1[3])};
  *(ushort8v*)(d + i) = o;
}

// ---------------- fused QKV GEMM ----------------
// grid 768 (XCD-swizzled): work = t*256 + tn*32 + tm; tile 128x128, BK=32.
// t=0 -> Qw (scaled 0.125*log2e), t=1 -> Kw, t=2 -> V^T [b*1024 + n][2048].
template <int WBF>
__global__ __launch_bounds__(256, 3) void gemm_qkv(
    const unsigned short* __restrict__ xb,
    const void* __restrict__ W0, const void* __restrict__ W1, const void* __restrict__ W2,
    const float* __restrict__ b0, const float* __restrict__ b1, const float* __restrict__ b2,
    unsigned short* __restrict__ Qw, unsigned short* __restrict__ Kw,
    unsigned short* __restrict__ Vt) {
  constexpr int K = 1024;
  __shared__ unsigned short As[2][128 * 32];
  __shared__ unsigned short Bs[2][128 * 32];
  const int tid = threadIdx.x, lane = tid & 63, w = tid >> 6;
  const int g = lane >> 4, ln = lane & 15;
  const int wm = (w >> 1) * 64, wn = (w & 1) * 64;
  const int work = ((int)blockIdx.x & 7) * 96 + ((int)blockIdx.x >> 3);
  const int t = work >> 8, tn = (work >> 5) & 7, tm = work & 31;
  const int m0 = tm * 128, n0 = tn * 128;
  const void* Wsel = t == 0 ? W0 : (t == 1 ? W1 : W2);
  const float* bsel = t == 0 ? b0 : (t == 1 ? b1 : b2);
  const float osc = t == 0 ? QSCALE : 1.0f;

  const unsigned short* Abase = xb + (size_t)(m0 + (tid >> 2)) * K + (tid & 3) * 8;
  const unsigned short* Bb16 = (const unsigned short*)Wsel + (size_t)(n0 + (tid >> 2)) * K + (tid & 3) * 8;
  const float* Bf32 = (const float*)Wsel + (size_t)(n0 + (tid >> 1)) * K + (tid & 1) * 16;
  const int bwoff = (tid >> 1) * 32 + (tid & 1) * 16;

  f32x4 acc[4][4] = {};

  gld16(Abase, &As[0][tid * 8]);
  gld16(Abase + (size_t)64 * K, &As[0][2048 + tid * 8]);
  if (WBF) {
    gld16(Bb16, &Bs[0][tid * 8]);
    gld16(Bb16 + (size_t)64 * K, &Bs[0][2048 + tid * 8]);
  } else {
    float4v u0 = *(const float4v*)Bf32, u1 = *(const float4v*)(Bf32 + 4);
    float4v u2 = *(const float4v*)(Bf32 + 8), u3 = *(const float4v*)(Bf32 + 12);
    ushort8v o0 = {f2bf(u0[0]), f2bf(u0[1]), f2bf(u0[2]), f2bf(u0[3]),
                   f2bf(u1[0]), f2bf(u1[1]), f2bf(u1[2]), f2bf(u1[3])};
    ushort8v o1 = {f2bf(u2[0]), f2bf(u2[1]), f2bf(u2[2]), f2bf(u2[3]),
                   f2bf(u3[0]), f2bf(u3[1]), f2bf(u3[2]), f2bf(u3[3])};
    *(ushort8v*)&Bs[0][bwoff] = o0;
    *(ushort8v*)&Bs[0][bwoff + 8] = o1;
  }

#pragma unroll 2
  for (int it = 0; it < 32; ++it) {
    __syncthreads();
    const int cur = it & 1, nxt = cur ^ 1;
    float4v u0, u1, u2, u3;
    if (it + 1 < 32) {
      const int k1 = (it + 1) * 32;
      gld16(Abase + k1, &As[nxt][tid * 8]);
      gld16(Abase + (size_t)64 * K + k1, &As[nxt][2048 + tid * 8]);
      if (WBF) {
        gld16(Bb16 + k1, &Bs[nxt][tid * 8]);
        gld16(Bb16 + (size_t)64 * K + k1, &Bs[nxt][2048 + tid * 8]);
      } else {
        u0 = *(const float4v*)(Bf32 + k1);
        u1 = *(const float4v*)(Bf32 + k1 + 4);
        u2 = *(const float4v*)(Bf32 + k1 + 8);
        u3 = *(const float4v*)(Bf32 + k1 + 12);
      }
    }
    short8 a[4], bfr[4];
#pragma unroll
    for (int fi = 0; fi < 4; ++fi)
      a[fi] = *(const short8*)&As[cur][(wm + fi * 16 + ln) * 32 + g * 8];
#pragma unroll
    for (int fj = 0; fj < 4; ++fj)
      bfr[fj] = *(const short8*)&Bs[cur][(wn + fj * 16 + ln) * 32 + g * 8];
#pragma unroll
    for (int fi = 0; fi < 4; ++fi)
#pragma unroll
      for (int fj = 0; fj < 4; ++fj) acc[fi][fj] = mfma16(a[fi], bfr[fj], acc[fi][fj]);
    if (!WBF && it + 1 < 32) {
      ushort8v o0 = {f2bf(u0[0]), f2bf(u0[1]), f2bf(u0[2]), f2bf(u0[3]),
                     f2bf(u1[0]), f2bf(u1[1]), f2bf(u1[2]), f2bf(u1[3])};
      ushort8v o1 = {f2bf(u2[0]), f2bf(u2[1]), f2bf(u2[2]), f2bf(u2[3]),
                     f2bf(u3[0]), f2bf(u3[1]), f2bf(u3[2]), f2bf(u3[3])};
      *(ushort8v*)&Bs[nxt][bwoff] = o0;
      *(ushort8v*)&Bs[nxt][bwoff + 8] = o1;
    }
  }

  if (t < 2) {
    unsigned short* Op = t == 0 ? Qw : Kw;
#pragma unroll
    for (int fi = 0; fi < 4; ++fi)
#pragma unroll
      for (int fj = 0; fj < 4; ++fj) {
        const int n = n0 + wn + fj * 16 + ln;
        const float bs = bsel[n];
#pragma unroll
        for (int rr = 0; rr < 4; ++rr) {
          const int m = m0 + wm + fi * 16 + 4 * g + rr;
          Op[(size_t)m * 1024 + n] = f2bf((acc[fi][fj][rr] + bs) * osc);
        }
      }
  } else {
    const int bb = m0 >> 11;
    const int s0 = (m0 & 2047) + wm;
#pragma unroll
    for (int fi = 0; fi < 4; ++fi)
#pragma unroll
      for (int fj = 0; fj < 4; ++fj) {
        const int n = n0 + wn + fj * 16 + ln;
        const float bs = bsel[n];
        ushort4v o = {f2bf(acc[fi][fj][0] + bs), f2bf(acc[fi][fj][1] + bs),
                      f2bf(acc[fi][fj][2] + bs), f2bf(acc[fi][fj][3] + bs)};
        *(ushort4v*)&Vt[(size_t)(bb * 1024 + n) * 2048 + s0 + fi * 16 + 4 * g] = o;
      }
  }
}

// ---------------- out projection: 128x128 tile, grid 256 ----------------
template <int WBF>
__global__ __launch_bounds__(256, 3) void gemm_o(const unsigned short* __restrict__ Cw,
                                                 const void* __restrict__ Wo,
                                                 const float* __restrict__ bo,
                                                 float* __restrict__ outp) {
  constexpr int K = 1024;
  __shared__ unsigned short As[2][128 * 32];
  __shared__ unsigned short Bs[2][128 * 32];
  const int tid = threadIdx.x, lane = tid & 63, w = tid >> 6;
  const int g = lane >> 4, ln = lane & 15;
  const int wm = (w >> 1) * 64, wn = (w & 1) * 64;
  const int work = ((int)blockIdx.x & 7) * 32 + ((int)blockIdx.x >> 3);
  const int m0 = (work & 31) * 128, n0 = (work >> 5) * 128;

  const unsigned short* Abase = Cw + (size_t)(m0 + (tid >> 2)) * K + (tid & 3) * 8;
  const unsigned short* Bb16 = (const unsigned short*)Wo + (size_t)(n0 + (tid >> 2)) * K + (tid & 3) * 8;
  const float* Bf32 = (const float*)Wo + (size_t)(n0 + (tid >> 1)) * K + (tid & 1) * 16;
  const int bwoff = (tid >> 1) * 32 + (tid & 1) * 16;

  f32x4 acc[4][4] = {};

  gld16(Abase, &As[0][tid * 8]);
  gld16(Abase + (size_t)64 * K, &As[0][2048 + tid * 8]);
  if (WBF) {
    gld16(Bb16, &Bs[0][tid * 8]);
    gld16(Bb16 + (size_t)64 * K, &Bs[0][2048 + tid * 8]);
  } else {
    float4v u0 = *(const float4v*)Bf32, u1 = *(const float4v*)(Bf32 + 4);
    float4v u2 = *(const float4v*)(Bf32 + 8), u3 = *(const float4v*)(Bf32 + 12);
    ushort8v o0 = {f2bf(u0[0]), f2bf(u0[1]), f2bf(u0[2]), f2bf(u0[3]),
                   f2bf(u1[0]), f2bf(u1[1]), f2bf(u1[2]), f2bf(u1[3])};
    ushort8v o1 = {f2bf(u2[0]), f2bf(u2[1]), f2bf(u2[2]), f2bf(u2[3]),
                   f2bf(u3[0]), f2bf(u3[1]), f2bf(u3[2]), f2bf(u3[3])};
    *(ushort8v*)&Bs[0][bwoff] = o0;
    *(ushort8v*)&Bs[0][bwoff + 8] = o1;
  }

#pragma unroll 2
  for (int it = 0; it < 32; ++it) {
    __syncthreads();
    const int cur = it & 1, nxt = cur ^ 1;
    float4v u0, u1, u2, u3;
    if (it + 1 < 32) {
      const int k1 = (it + 1) * 32;
      gld16(Abase + k1, &As[nxt][tid * 8]);
      gld16(Abase + (size_t)64 * K + k1, &As[nxt][2048 + tid * 8]);
      if (WBF) {
        gld16(Bb16 + k1, &Bs[nxt][tid * 8]);
        gld16(Bb16 + (size_t)64 * K + k1, &Bs[nxt][2048 + tid * 8]);
      } else {
        u0 = *(const float4v*)(Bf32 + k1);
        u1 = *(const float4v*)(Bf32 + k1 + 4);
        u2 = *(const float4v*)(Bf32 + k1 + 8);
        u3 = *(const float4v*)(Bf32 + k1 + 12);
      }
    }
    short8 a[4], bfr[4];
#pragma unroll
    for (int fi = 0; fi < 4; ++fi)
      a[fi] = *(const short8*)&As[cur][(wm + fi * 16 + ln) * 32 + g * 8];
#pragma unroll
    for (int fj = 0; fj < 4; ++fj)
      bfr[fj] = *(const short8*)&Bs[cur][(wn + fj * 16 + ln) * 32 + g * 8];
#pragma unroll
    for (int fi = 0; fi < 4; ++fi)
#pragma unroll
      for (int fj = 0; fj < 4; ++fj) acc[fi][fj] = mfma16(a[fi], bfr[fj], acc[fi][fj]);
    if (!WBF && it + 1 < 32) {
      ushort8v o0 = {f2bf(u0[0]), f2bf(u0[1]), f2bf(u0[2]), f2bf(u0[3]),
                     f2bf(u1[0]), f2bf(u1[1]), f2bf(u1[2]), f2bf(u1[3])};
      ushort8v o1 = {f2bf(u2[0]), f2bf(u2[1]), f2bf(u2[2]), f2bf(u2[3]),
                     f2bf(u3[0]), f2bf(u3[1]), f2bf(u3[2]), f2bf(u3[3])};
      *(ushort8v*)&Bs[nxt][bwoff] = o0;
      *(ushort8v*)&Bs[nxt][bwoff + 8] = o1;
    }
  }

#pragma unroll
  for (int fi = 0; fi < 4; ++fi)
#pragma unroll
    for (int fj = 0; fj < 4; ++fj) {
      const int n = n0 + wn + fj * 16 + ln;
      const float bs = bo[n];
#pragma unroll
      for (int rr = 0; rr < 4; ++rr) {
        const int m = m0 + wm + fi * 16 + 4 * g + rr;
        outp[(size_t)m * 1024 + n] = acc[fi][fj][rr] + bs;
      }
    }
}

// ---------------- Attention ----------------
// 256 threads = 4 waves, each owns TWO 16-row q strips (32 q). Q pre-scaled
// 0.125*log2e. Swapped QK^T (A=K, B=Q). K/V staged via global_load_lds with
// 16B-block XOR swizzle (src+read sides). Pass-2 C-init = lbias = -log2(l)
// so p = 2^(S+lbias) needs no multiply. Q fragments direct global->reg.
__global__ __launch_bounds__(256, 3) void attn_kernel(
    const unsigned short* __restrict__ Qg, const unsigned short* __restrict__ Kg,
    const unsigned short* __restrict__ Vt, float* __restrict__ attn_out,
    unsigned short* __restrict__ ctx) {
  constexpr int LDP = 72;
  __shared__ unsigned short Ps[128 * LDP];
  __shared__ unsigned short Ks[2][64 * 64];
  __shared__ unsigned short Vs[2][64 * 64];
  const int tid = threadIdx.x, lane = tid & 63, w = tid >> 6;  // w in 0..3
  const int g = lane >> 4, ln = lane & 15;
  const int work = ((int)blockIdx.x & 7) * 64 + ((int)blockIdx.x >> 3);
  const int qt = work & 15, h = (work >> 4) & 15, b = work >> 8;
  const int q0 = qt * 128;
  const size_t kbase = (size_t)b * 2048 * 1024 + (size_t)h * 64;   // [token][1024]
  const size_t vbase = ((size_t)b * 1024 + h * 64) * 2048;         // [d-row][2048]

  // Q fragments: strips s=0,1 (rows w*32+s*16+ln), k-halves hh=0,1. Direct global.
  short8 qf[2][2];
#pragma unroll
  for (int s = 0; s < 2; ++s)
#pragma unroll
    for (int hh = 0; hh < 2; ++hh)
      qf[s][hh] = *(const short8*)(Qg + kbase +
                                   (size_t)(q0 + w * 32 + s * 16 + ln) * 1024 +
                                   hh * 32 + 8 * g);

  const int sr = tid >> 3, sb = tid & 7;        // 32 staging rows per gld16 call
  const int swz = ((sb ^ (sr & 7)) * 8);
  const unsigned short* Ksrc = Kg + kbase + (size_t)sr * 1024 + swz;
  const unsigned short* Vsrc = Vt + vbase + (size_t)sr * 2048 + swz;

  // ---- pass 1: denominators per strip ----
  float lp0 = 0.f, lp1 = 0.f;
  gld16(Ksrc, &Ks[0][tid * 8]);
  gld16(Ksrc + (size_t)32 * 1024, &Ks[0][2048 + tid * 8]);
#pragma unroll 2
  for (int kc = 0; kc < 32; ++kc) {
    __syncthreads();
    if (kc + 1 < 32) {
      const unsigned short* s = Ksrc + (size_t)(kc + 1) * 64 * 1024;
      gld16(s, &Ks[(kc + 1) & 1][tid * 8]);
      gld16(s + (size_t)32 * 1024, &Ks[(kc + 1) & 1][2048 + tid * 8]);
    }
    const unsigned short* Kc = Ks[kc & 1];
#pragma unroll
    for (int fk = 0; fk < 4; ++fk) {
      const int row = fk * 16 + ln;
      const short8 kf0 = *(const short8*)&Kc[row * 64 + ((g ^ (ln & 7)) * 8)];
      const short8 kf1 = *(const short8*)&Kc[row * 64 + (((4 + g) ^ (ln & 7)) * 8)];
      f32x4 z0 = {0.f, 0.f, 0.f, 0.f}, z1 = {0.f, 0.f, 0.f, 0.f};
      __builtin_amdgcn_s_setprio(1);
      z0 = mfma16(kf0, qf[0][0], z0);
      z0 = mfma16(kf1, qf[0][1], z0);
      z1 = mfma16(kf0, qf[1][0], z1);
      z1 = mfma16(kf1, qf[1][1], z1);
      __builtin_amdgcn_s_setprio(0);
      lp0 += exp2v(z0[0]) + exp2v(z0[1]) + exp2v(z0[2]) + exp2v(z0[3]);
      lp1 += exp2v(z1[0]) + exp2v(z1[1]) + exp2v(z1[2]) + exp2v(z1[3]);
    }
  }
  lp0 += __shfl_xor(lp0, 16);
  lp0 += __shfl_xor(lp0, 32);
  lp1 += __shfl_xor(lp1, 16);
  lp1 += __shfl_xor(lp1, 32);
  const float lb0 = -log2f(lp0), lb1 = -log2f(lp1);

  // ---- pass 2: attn = 2^(S+lbias) stores + PV ----
  __syncthreads();
  gld16(Ksrc, &Ks[0][tid * 8]);
  gld16(Ksrc + (size_t)32 * 1024, &Ks[0][2048 + tid * 8]);
  gld16(Vsrc, &Vs[0][tid * 8]);
  gld16(Vsrc + (size_t)32 * 2048, &Vs[0][2048 + tid * 8]);
  f32x4 c_[2][4] = {};
  const size_t attnbase = ((size_t)(b * 16 + h) * 2048 + q0 + w * 32) * 2048;
#pragma unroll 2
  for (int kc = 0; kc < 32; ++kc) {
    __syncthreads();
    if (kc + 1 < 32) {
      const unsigned short* s = Ksrc + (size_t)(kc + 1) * 64 * 1024;
      gld16(s, &Ks[(kc + 1) & 1][tid * 8]);
      gld16(s + (size_t)32 * 1024, &Ks[(kc + 1) & 1][2048 + tid * 8]);
      const unsigned short* v = Vsrc + (kc + 1) * 64;
      gld16(v, &Vs[(kc + 1) & 1][tid * 8]);
      gld16(v + (size_t)32 * 2048, &Vs[(kc + 1) & 1][2048 + tid * 8]);
    }
    const unsigned short* Kc = Ks[kc & 1];
    const unsigned short* Vc = Vs[kc & 1];
#pragma unroll
    for (int fk = 0; fk < 4; ++fk) {
      const int row = fk * 16 + ln;
      const short8 kf0 = *(const short8*)&Kc[row * 64 + ((g ^ (ln & 7)) * 8)];
      const short8 kf1 = *(const short8*)&Kc[row * 64 + (((4 + g) ^ (ln & 7)) * 8)];
      f32x4 z0 = {lb0, lb0, lb0, lb0}, z1 = {lb1, lb1, lb1, lb1};
      __builtin_amdgcn_s_setprio(1);
      z0 = mfma16(kf0, qf[0][0], z0);
      z0 = mfma16(kf1, qf[0][1], z0);
      z1 = mfma16(kf0, qf[1][0], z1);
      z1 = mfma16(kf1, qf[1][1], z1);
      __builtin_amdgcn_s_setprio(0);
      float4v pv0 = {exp2v(z0[0]), exp2v(z0[1]), exp2v(z0[2]), exp2v(z0[3])};
      float4v pv1 = {exp2v(z1[0]), exp2v(z1[1]), exp2v(z1[2]), exp2v(z1[3])};
      const int coff = kc * 64 + fk * 16 + 4 * g;
      *(float4v*)&attn_out[attnbase + (size_t)ln * 2048 + coff] = pv0;
      *(float4v*)&attn_out[attnbase + (size_t)(16 + ln) * 2048 + coff] = pv1;
      ushort4v pb0 = {f2bf(pv0[0]), f2bf(pv0[1]), f2bf(pv0[2]), f2bf(pv0[3])};
      ushort4v pb1 = {f2bf(pv1[0]), f2bf(pv1[1]), f2bf(pv1[2]), f2bf(pv1[3])};
      *(ushort4v*)&Ps[(w * 32 + ln) * LDP + fk * 16 + 4 * g] = pb0;
      *(ushort4v*)&Ps[(w * 32 + 16 + ln) * LDP + fk * 16 + 4 * g] = pb1;
    }
#pragma unroll
    for (int ks = 0; ks < 2; ++ks) {
      const short8 pa0 = *(const short8*)&Ps[(w * 32 + ln) * LDP + ks * 32 + 8 * g];
      const short8 pa1 = *(const short8*)&Ps[(w * 32 + 16 + ln) * LDP + ks * 32 + 8 * g];
      __builtin_amdgcn_s_setprio(1);
#pragma unroll
      for (int fd = 0; fd < 4; ++fd) {
        const int d = fd * 16 + ln;
        const short8 vb = *(const short8*)&Vc[d * 64 + (((ks * 4 + g) ^ (ln & 7)) * 8)];
        c_[0][fd] = mfma16(pa0, vb, c_[0][fd]);
        c_[1][fd] = mfma16(pa1, vb, c_[1][fd]);
      }
      __builtin_amdgcn_s_setprio(0);
    }
  }

  // ctx -> bf16 ws [token][h*64+d]
#pragma unroll
  for (int s = 0; s < 2; ++s)
#pragma unroll
    for (int fd = 0; fd < 4; ++fd)
#pragma unroll
      for (int rr = 0; rr < 4; ++rr) {
        const int q = w * 32 + s * 16 + 4 * g + rr;
        ctx[(size_t)(b * 2048 + q0 + q) * 1024 + h * 64 + fd * 16 + ln] =
            f2bf(c_[s][fd][rr]);
      }
}

extern "C" void kernel_launch(void* const* d_in, const int* in_sizes, int n_in,
                              void* d_out, int out_size, void* d_ws, size_t ws_size,
                              hipStream_t stream) {
  const float* x  = (const float*)d_in[0];
  const float* Wq = (const float*)d_in[1];
  const float* bq = (const float*)d_in[2];
  const float* Wk = (const float*)d_in[3];
  const float* bk = (const float*)d_in[4];
  const float* Wv = (const float*)d_in[5];
  const float* bv = (const float*)d_in[6];
  const float* Wo = (const float*)d_in[7];
  const float* bo = (const float*)d_in[8];

  float* outp = (float*)d_out;
  float* attnp = outp + (size_t)4194304;

  unsigned short* Qw = (unsigned short*)d_ws;
  unsigned short* Kw = Qw + (size_t)4194304;
  unsigned short* Vt = Kw + (size_t)4194304;
  unsigned short* Cw = Vt + (size_t)4194304;  // ctx; aliased as xb before attn

  const bool wbf = ws_size >= (size_t)40 * 1024 * 1024;
  dim3 blk(256, 1, 1);

  if (wbf) {
    unsigned short* Wqb = Cw + (size_t)4194304;
    unsigned short* Wkb = Wqb + (size_t)1048576;
    unsigned short* Wvb = Wkb + (size_t)1048576;
    unsigned short* Wob = Wvb + (size_t)1048576;
    cvt_all<<<dim3(4096), blk, 0, stream>>>(x, Wq, Wk, Wv, Wo, Cw, Wqb, Wkb, Wvb, Wob);
    gemm_qkv<1><<<dim3(768), blk, 0, stream>>>(Cw, Wqb, Wkb, Wvb, bq, bk, bv, Qw, Kw, Vt);
    attn_kernel<<<dim3(512), blk, 0, stream>>>(Qw, Kw, Vt, attnp, Cw);
    gemm_o<1><<<dim3(256), blk, 0, stream>>>(Cw, Wob, bo, outp);
  } else {
    cvt_all<<<dim3(2048), blk, 0, stream>>>(x, Wq, Wk, Wv, Wo, Cw, nullptr, nullptr,
                                            nullptr, nullptr);
    gemm_qkv<0><<<dim3(768), blk, 0, stream>>>(Cw, Wq, Wk, Wv, bq, bk, bv, Qw, Kw, Vt);
    attn_kernel<<<dim3(512), blk, 0, stream>>>(Qw, Kw, Vt, attnp, Cw);
    gemm_o<0><<<dim3(256), blk, 0, stream>>>(Cw, Wo, bo, outp);
  }
}

// Round 8
// 244.800 us; speedup vs baseline: 1.0470x; 1.0470x over previous
//
#include <hip/hip_runtime.h>
#include <hip/hip_bf16.h>

// MultiHeadSelfAttention: B=2, S=2048, D=1024, H=16, HD=64
// d_out = out [2,2048,1024] fp32 ++ attn [2,16,2048,2048] fp32.
// bf16 MFMA 16x16x32, fp32 accum. global_load_lds(16B) staging, double-buffered
// single-barrier loops. V^T from the V-projection epilogue. Attention: 512-thread
// blocks (8 waves x 16 q-rows, 16 waves/CU), 2-pass no-max softmax, exp2 folding
// (Q pre-scaled 0.125*log2e), pass-2 normalization folded into MFMA C-init
// (lbias = -log2 l), Q fragments direct global->reg.

typedef __attribute__((ext_vector_type(8))) __bf16 bf16x8;
typedef __attribute__((ext_vector_type(8))) short short8;
typedef __attribute__((ext_vector_type(4))) float f32x4;
typedef __attribute__((ext_vector_type(4))) float float4v;
typedef __attribute__((ext_vector_type(4))) unsigned short ushort4v;
typedef __attribute__((ext_vector_type(8))) unsigned short ushort8v;

#define DEV static __device__ __forceinline__

DEV unsigned short f2bf(float f) {
  unsigned int u = __builtin_bit_cast(unsigned int, f);
  u += 0x7FFFu + ((u >> 16) & 1u);  // RNE
  return (unsigned short)(u >> 16);
}

DEV float exp2v(float x) {  // 2^x via compiler-managed intrinsic (hazard-safe)
#if __has_builtin(__builtin_amdgcn_exp2f)
  return __builtin_amdgcn_exp2f(x);
#else
  return exp2f(x);
#endif
}

DEV f32x4 mfma16(short8 a, short8 b, f32x4 c) {
  return __builtin_amdgcn_mfma_f32_16x16x32_bf16(
      __builtin_bit_cast(bf16x8, a), __builtin_bit_cast(bf16x8, b), c, 0, 0, 0);
}

DEV void gld16(const void* g, void* l) {
  __builtin_amdgcn_global_load_lds(
      (const __attribute__((address_space(1))) void*)g,
      (__attribute__((address_space(3))) void*)l, 16, 0, 0);
}

#define QSCALE 0.18033688011112042f  // 0.125 * log2(e)

// ---------------- fused fp32 -> bf16 bulk convert (x + 4 weights) ------------
__global__ __launch_bounds__(256) void cvt_all(
    const float* __restrict__ x, const float* __restrict__ wq,
    const float* __restrict__ wk, const float* __restrict__ wv,
    const float* __restrict__ wo, unsigned short* __restrict__ xb,
    unsigned short* __restrict__ wqb, unsigned short* __restrict__ wkb,
    unsigned short* __restrict__ wvb, unsigned short* __restrict__ wob) {
  const int bid = blockIdx.x;
  const float* s;
  unsigned short* d;
  int base;
  if (bid < 2048) {
    s = x; d = xb; base = bid * 2048;
  } else {
    const int j = bid - 2048, sel = j >> 9;
    s = sel == 0 ? wq : (sel == 1 ? wk : (sel == 2 ? wv : wo));
    d = sel == 0 ? wqb : (sel == 1 ? wkb : (sel == 2 ? wvb : wob));
    base = (j & 511) * 2048;
  }
  const int i = base + threadIdx.x * 8;
  float4v v0 = *(const float4v*)(s + i);
  float4v v1 = *(const float4v*)(s + i + 4);
  ushort8v o = {f2bf(v0[0]), f2bf(v0[1]), f2bf(v0[2]), f2bf(v0[3]),
                f2bf(v1[0]), f2bf(v1[1]), f2bf(v1[2]), f2bf(v1[3])};
  *(ushort8v*)(d + i) = o;
}

// ---------------- fused QKV GEMM ----------------
// grid 768 (XCD-swizzled): work = t*256 + tn*32 + tm; tile 128x128, BK=32.
// t=0 -> Qw (scaled 0.125*log2e), t=1 -> Kw, t=2 -> V^T [b*1024 + n][2048].
template <int WBF>
__global__ __launch_bounds__(256, 3) void gemm_qkv(
    const unsigned short* __restrict__ xb,
    const void* __restrict__ W0, const void* __restrict__ W1, const void* __restrict__ W2,
    const float* __restrict__ b0, const float* __restrict__ b1, const float* __restrict__ b2,
    unsigned short* __restrict__ Qw, unsigned short* __restrict__ Kw,
    unsigned short* __restrict__ Vt) {
  constexpr int K = 1024;
  __shared__ unsigned short As[2][128 * 32];
  __shared__ unsigned short Bs[2][128 * 32];
  const int tid = threadIdx.x, lane = tid & 63, w = tid >> 6;
  const int g = lane >> 4, ln = lane & 15;
  const int wm = (w >> 1) * 64, wn = (w & 1) * 64;
  const int work = ((int)blockIdx.x & 7) * 96 + ((int)blockIdx.x >> 3);
  const int t = work >> 8, tn = (work >> 5) & 7, tm = work & 31;
  const int m0 = tm * 128, n0 = tn * 128;
  const void* Wsel = t == 0 ? W0 : (t == 1 ? W1 : W2);
  const float* bsel = t == 0 ? b0 : (t == 1 ? b1 : b2);
  const float osc = t == 0 ? QSCALE : 1.0f;

  const unsigned short* Abase = xb + (size_t)(m0 + (tid >> 2)) * K + (tid & 3) * 8;
  const unsigned short* Bb16 = (const unsigned short*)Wsel + (size_t)(n0 + (tid >> 2)) * K + (tid & 3) * 8;
  const float* Bf32 = (const float*)Wsel + (size_t)(n0 + (tid >> 1)) * K + (tid & 1) * 16;
  const int bwoff = (tid >> 1) * 32 + (tid & 1) * 16;

  f32x4 acc[4][4] = {};

  gld16(Abase, &As[0][tid * 8]);
  gld16(Abase + (size_t)64 * K, &As[0][2048 + tid * 8]);
  if (WBF) {
    gld16(Bb16, &Bs[0][tid * 8]);
    gld16(Bb16 + (size_t)64 * K, &Bs[0][2048 + tid * 8]);
  } else {
    float4v u0 = *(const float4v*)Bf32, u1 = *(const float4v*)(Bf32 + 4);
    float4v u2 = *(const float4v*)(Bf32 + 8), u3 = *(const float4v*)(Bf32 + 12);
    ushort8v o0 = {f2bf(u0[0]), f2bf(u0[1]), f2bf(u0[2]), f2bf(u0[3]),
                   f2bf(u1[0]), f2bf(u1[1]), f2bf(u1[2]), f2bf(u1[3])};
    ushort8v o1 = {f2bf(u2[0]), f2bf(u2[1]), f2bf(u2[2]), f2bf(u2[3]),
                   f2bf(u3[0]), f2bf(u3[1]), f2bf(u3[2]), f2bf(u3[3])};
    *(ushort8v*)&Bs[0][bwoff] = o0;
    *(ushort8v*)&Bs[0][bwoff + 8] = o1;
  }

#pragma unroll 2
  for (int it = 0; it < 32; ++it) {
    __syncthreads();
    const int cur = it & 1, nxt = cur ^ 1;
    float4v u0, u1, u2, u3;
    if (it + 1 < 32) {
      const int k1 = (it + 1) * 32;
      gld16(Abase + k1, &As[nxt][tid * 8]);
      gld16(Abase + (size_t)64 * K + k1, &As[nxt][2048 + tid * 8]);
      if (WBF) {
        gld16(Bb16 + k1, &Bs[nxt][tid * 8]);
        gld16(Bb16 + (size_t)64 * K + k1, &Bs[nxt][2048 + tid * 8]);
      } else {
        u0 = *(const float4v*)(Bf32 + k1);
        u1 = *(const float4v*)(Bf32 + k1 + 4);
        u2 = *(const float4v*)(Bf32 + k1 + 8);
        u3 = *(const float4v*)(Bf32 + k1 + 12);
      }
    }
    short8 a[4], bfr[4];
#pragma unroll
    for (int fi = 0; fi < 4; ++fi)
      a[fi] = *(const short8*)&As[cur][(wm + fi * 16 + ln) * 32 + g * 8];
#pragma unroll
    for (int fj = 0; fj < 4; ++fj)
      bfr[fj] = *(const short8*)&Bs[cur][(wn + fj * 16 + ln) * 32 + g * 8];
#pragma unroll
    for (int fi = 0; fi < 4; ++fi)
#pragma unroll
      for (int fj = 0; fj < 4; ++fj) acc[fi][fj] = mfma16(a[fi], bfr[fj], acc[fi][fj]);
    if (!WBF && it + 1 < 32) {
      ushort8v o0 = {f2bf(u0[0]), f2bf(u0[1]), f2bf(u0[2]), f2bf(u0[3]),
                     f2bf(u1[0]), f2bf(u1[1]), f2bf(u1[2]), f2bf(u1[3])};
      ushort8v o1 = {f2bf(u2[0]), f2bf(u2[1]), f2bf(u2[2]), f2bf(u2[3]),
                     f2bf(u3[0]), f2bf(u3[1]), f2bf(u3[2]), f2bf(u3[3])};
      *(ushort8v*)&Bs[nxt][bwoff] = o0;
      *(ushort8v*)&Bs[nxt][bwoff + 8] = o1;
    }
  }

  if (t < 2) {
    unsigned short* Op = t == 0 ? Qw : Kw;
#pragma unroll
    for (int fi = 0; fi < 4; ++fi)
#pragma unroll
      for (int fj = 0; fj < 4; ++fj) {
        const int n = n0 + wn + fj * 16 + ln;
        const float bs = bsel[n];
#pragma unroll
        for (int rr = 0; rr < 4; ++rr) {
          const int m = m0 + wm + fi * 16 + 4 * g + rr;
          Op[(size_t)m * 1024 + n] = f2bf((acc[fi][fj][rr] + bs) * osc);
        }
      }
  } else {
    const int bb = m0 >> 11;
    const int s0 = (m0 & 2047) + wm;
#pragma unroll
    for (int fi = 0; fi < 4; ++fi)
#pragma unroll
      for (int fj = 0; fj < 4; ++fj) {
        const int n = n0 + wn + fj * 16 + ln;
        const float bs = bsel[n];
        ushort4v o = {f2bf(acc[fi][fj][0] + bs), f2bf(acc[fi][fj][1] + bs),
                      f2bf(acc[fi][fj][2] + bs), f2bf(acc[fi][fj][3] + bs)};
        *(ushort4v*)&Vt[(size_t)(bb * 1024 + n) * 2048 + s0 + fi * 16 + 4 * g] = o;
      }
  }
}

// ---------------- out projection: 128x128 tile, grid 256 ----------------
template <int WBF>
__global__ __launch_bounds__(256, 3) void gemm_o(const unsigned short* __restrict__ Cw,
                                                 const void* __restrict__ Wo,
                                                 const float* __restrict__ bo,
                                                 float* __restrict__ outp) {
  constexpr int K = 1024;
  __shared__ unsigned short As[2][128 * 32];
  __shared__ unsigned short Bs[2][128 * 32];
  const int tid = threadIdx.x, lane = tid & 63, w = tid >> 6;
  const int g = lane >> 4, ln = lane & 15;
  const int wm = (w >> 1) * 64, wn = (w & 1) * 64;
  const int work = ((int)blockIdx.x & 7) * 32 + ((int)blockIdx.x >> 3);
  const int m0 = (work & 31) * 128, n0 = (work >> 5) * 128;

  const unsigned short* Abase = Cw + (size_t)(m0 + (tid >> 2)) * K + (tid & 3) * 8;
  const unsigned short* Bb16 = (const unsigned short*)Wo + (size_t)(n0 + (tid >> 2)) * K + (tid & 3) * 8;
  const float* Bf32 = (const float*)Wo + (size_t)(n0 + (tid >> 1)) * K + (tid & 1) * 16;
  const int bwoff = (tid >> 1) * 32 + (tid & 1) * 16;

  f32x4 acc[4][4] = {};

  gld16(Abase, &As[0][tid * 8]);
  gld16(Abase + (size_t)64 * K, &As[0][2048 + tid * 8]);
  if (WBF) {
    gld16(Bb16, &Bs[0][tid * 8]);
    gld16(Bb16 + (size_t)64 * K, &Bs[0][2048 + tid * 8]);
  } else {
    float4v u0 = *(const float4v*)Bf32, u1 = *(const float4v*)(Bf32 + 4);
    float4v u2 = *(const float4v*)(Bf32 + 8), u3 = *(const float4v*)(Bf32 + 12);
    ushort8v o0 = {f2bf(u0[0]), f2bf(u0[1]), f2bf(u0[2]), f2bf(u0[3]),
                   f2bf(u1[0]), f2bf(u1[1]), f2bf(u1[2]), f2bf(u1[3])};
    ushort8v o1 = {f2bf(u2[0]), f2bf(u2[1]), f2bf(u2[2]), f2bf(u2[3]),
                   f2bf(u3[0]), f2bf(u3[1]), f2bf(u3[2]), f2bf(u3[3])};
    *(ushort8v*)&Bs[0][bwoff] = o0;
    *(ushort8v*)&Bs[0][bwoff + 8] = o1;
  }

#pragma unroll 2
  for (int it = 0; it < 32; ++it) {
    __syncthreads();
    const int cur = it & 1, nxt = cur ^ 1;
    float4v u0, u1, u2, u3;
    if (it + 1 < 32) {
      const int k1 = (it + 1) * 32;
      gld16(Abase + k1, &As[nxt][tid * 8]);
      gld16(Abase + (size_t)64 * K + k1, &As[nxt][2048 + tid * 8]);
      if (WBF) {
        gld16(Bb16 + k1, &Bs[nxt][tid * 8]);
        gld16(Bb16 + (size_t)64 * K + k1, &Bs[nxt][2048 + tid * 8]);
      } else {
        u0 = *(const float4v*)(Bf32 + k1);
        u1 = *(const float4v*)(Bf32 + k1 + 4);
        u2 = *(const float4v*)(Bf32 + k1 + 8);
        u3 = *(const float4v*)(Bf32 + k1 + 12);
      }
    }
    short8 a[4], bfr[4];
#pragma unroll
    for (int fi = 0; fi < 4; ++fi)
      a[fi] = *(const short8*)&As[cur][(wm + fi * 16 + ln) * 32 + g * 8];
#pragma unroll
    for (int fj = 0; fj < 4; ++fj)
      bfr[fj] = *(const short8*)&Bs[cur][(wn + fj * 16 + ln) * 32 + g * 8];
#pragma unroll
    for (int fi = 0; fi < 4; ++fi)
#pragma unroll
      for (int fj = 0; fj < 4; ++fj) acc[fi][fj] = mfma16(a[fi], bfr[fj], acc[fi][fj]);
    if (!WBF && it + 1 < 32) {
      ushort8v o0 = {f2bf(u0[0]), f2bf(u0[1]), f2bf(u0[2]), f2bf(u0[3]),
                     f2bf(u1[0]), f2bf(u1[1]), f2bf(u1[2]), f2bf(u1[3])};
      ushort8v o1 = {f2bf(u2[0]), f2bf(u2[1]), f2bf(u2[2]), f2bf(u2[3]),
                     f2bf(u3[0]), f2bf(u3[1]), f2bf(u3[2]), f2bf(u3[3])};
      *(ushort8v*)&Bs[nxt][bwoff] = o0;
      *(ushort8v*)&Bs[nxt][bwoff + 8] = o1;
    }
  }

#pragma unroll
  for (int fi = 0; fi < 4; ++fi)
#pragma unroll
    for (int fj = 0; fj < 4; ++fj) {
      const int n = n0 + wn + fj * 16 + ln;
      const float bs = bo[n];
#pragma unroll
      for (int rr = 0; rr < 4; ++rr) {
        const int m = m0 + wm + fi * 16 + 4 * g + rr;
        outp[(size_t)m * 1024 + n] = acc[fi][fj][rr] + bs;
      }
    }
}

// ---------------- Attention ----------------
// 512 threads = 8 waves, each owns a 16-row q strip. Q pre-scaled 0.125*log2e.
// Swapped QK^T (A=K, B=Q): lane ln = q col, keys contiguous-4 per reg quartet.
// K/V staged by global_load_lds into linear LDS with 16B-block XOR swizzle
// (source-side + read-side). Double-buffered, 1 barrier per chunk.
// Pass-2 C-init = lbias = -log2(l): p = 2^(S+lbias), no per-element multiply.
__global__ __launch_bounds__(512, 4) void attn_kernel(
    const unsigned short* __restrict__ Qg, const unsigned short* __restrict__ Kg,
    const unsigned short* __restrict__ Vt, float* __restrict__ attn_out,
    unsigned short* __restrict__ ctx) {
  constexpr int LDP = 72;
  __shared__ unsigned short Ps[128 * LDP];
  __shared__ unsigned short Ks[2][64 * 64];
  __shared__ unsigned short Vs[2][64 * 64];
  const int tid = threadIdx.x, lane = tid & 63, w = tid >> 6;
  const int g = lane >> 4, ln = lane & 15;
  const int work = ((int)blockIdx.x & 7) * 64 + ((int)blockIdx.x >> 3);
  const int qt = work & 15, h = (work >> 4) & 15, b = work >> 8;
  const int q0 = qt * 128;
  const size_t kbase = (size_t)b * 2048 * 1024 + (size_t)h * 64;   // [token][1024]
  const size_t vbase = ((size_t)b * 1024 + h * 64) * 2048;         // [d-row][2048]

  // Q fragments direct global->reg: row = q0 + w*16 + ln, k-halves hh=0,1.
  short8 qf[2];
#pragma unroll
  for (int hh = 0; hh < 2; ++hh)
    qf[hh] = *(const short8*)(Qg + kbase + (size_t)(q0 + w * 16 + ln) * 1024 +
                              hh * 32 + 8 * g);

  const int sr = tid >> 3, sb = tid & 7;
  const int swz = ((sb ^ (sr & 7)) * 8);
  const unsigned short* Ksrc = Kg + kbase + (size_t)sr * 1024 + swz;
  const unsigned short* Vsrc = Vt + vbase + (size_t)sr * 2048 + swz;

  // ---- pass 1: denominators ----
  float lp = 0.f;
  gld16(Ksrc, &Ks[0][tid * 8]);
#pragma unroll 2
  for (int kc = 0; kc < 32; ++kc) {
    __syncthreads();
    if (kc + 1 < 32)
      gld16(Ksrc + (size_t)(kc + 1) * 64 * 1024, &Ks[(kc + 1) & 1][tid * 8]);
    const unsigned short* Kc = Ks[kc & 1];
#pragma unroll
    for (int fk = 0; fk < 4; ++fk) {
      const int row = fk * 16 + ln;
      const short8 kf0 = *(const short8*)&Kc[row * 64 + ((g ^ (ln & 7)) * 8)];
      const short8 kf1 = *(const short8*)&Kc[row * 64 + (((4 + g) ^ (ln & 7)) * 8)];
      f32x4 z = {0.f, 0.f, 0.f, 0.f};
      __builtin_amdgcn_s_setprio(1);
      z = mfma16(kf0, qf[0], z);
      z = mfma16(kf1, qf[1], z);
      __builtin_amdgcn_s_setprio(0);
      lp += exp2v(z[0]) + exp2v(z[1]) + exp2v(z[2]) + exp2v(z[3]);
    }
  }
  lp += __shfl_xor(lp, 16);
  lp += __shfl_xor(lp, 32);
  const float lb = -log2f(lp);

  // ---- pass 2: attn = 2^(S+lbias) (float4 stores via L2) + PV ----
  __syncthreads();
  gld16(Ksrc, &Ks[0][tid * 8]);
  gld16(Vsrc, &Vs[0][tid * 8]);
  f32x4 c_[4] = {};
  const size_t attnbase = ((size_t)(b * 16 + h) * 2048 + q0 + w * 16) * 2048;
#pragma unroll 2
  for (int kc = 0; kc < 32; ++kc) {
    __syncthreads();
    if (kc + 1 < 32) {
      gld16(Ksrc + (size_t)(kc + 1) * 64 * 1024, &Ks[(kc + 1) & 1][tid * 8]);
      gld16(Vsrc + (kc + 1) * 64, &Vs[(kc + 1) & 1][tid * 8]);
    }
    const unsigned short* Kc = Ks[kc & 1];
    const unsigned short* Vc = Vs[kc & 1];
#pragma unroll
    for (int fk = 0; fk < 4; ++fk) {
      const int row = fk * 16 + ln;
      const short8 kf0 = *(const short8*)&Kc[row * 64 + ((g ^ (ln & 7)) * 8)];
      const short8 kf1 = *(const short8*)&Kc[row * 64 + (((4 + g) ^ (ln & 7)) * 8)];
      f32x4 z = {lb, lb, lb, lb};
      __builtin_amdgcn_s_setprio(1);
      z = mfma16(kf0, qf[0], z);
      z = mfma16(kf1, qf[1], z);
      __builtin_amdgcn_s_setprio(0);
      float4v pv = {exp2v(z[0]), exp2v(z[1]), exp2v(z[2]), exp2v(z[3])};
      *(float4v*)&attn_out[attnbase + (size_t)ln * 2048 + kc * 64 + fk * 16 + 4 * g] = pv;
      ushort4v pb = {f2bf(pv[0]), f2bf(pv[1]), f2bf(pv[2]), f2bf(pv[3])};
      *(ushort4v*)&Ps[(w * 16 + ln) * LDP + fk * 16 + 4 * g] = pb;
    }
#pragma unroll
    for (int ks = 0; ks < 2; ++ks) {
      const short8 pa = *(const short8*)&Ps[(w * 16 + ln) * LDP + ks * 32 + 8 * g];
      __builtin_amdgcn_s_setprio(1);
#pragma unroll
      for (int fd = 0; fd < 4; ++fd) {
        const int d = fd * 16 + ln;
        const short8 vb = *(const short8*)&Vc[d * 64 + (((ks * 4 + g) ^ (ln & 7)) * 8)];
        c_[fd] = mfma16(pa, vb, c_[fd]);
      }
      __builtin_amdgcn_s_setprio(0);
    }
  }

  // ctx -> bf16 ws [token][h*64+d]
#pragma unroll
  for (int fd = 0; fd < 4; ++fd)
#pragma unroll
    for (int rr = 0; rr < 4; ++rr) {
      const int q = w * 16 + 4 * g + rr;
      ctx[(size_t)(b * 2048 + q0 + q) * 1024 + h * 64 + fd * 16 + ln] = f2bf(c_[fd][rr]);
    }
}

extern "C" void kernel_launch(void* const* d_in, const int* in_sizes, int n_in,
                              void* d_out, int out_size, void* d_ws, size_t ws_size,
                              hipStream_t stream) {
  const float* x  = (const float*)d_in[0];
  const float* Wq = (const float*)d_in[1];
  const float* bq = (const float*)d_in[2];
  const float* Wk = (const float*)d_in[3];
  const float* bk = (const float*)d_in[4];
  const float* Wv = (const float*)d_in[5];
  const float* bv = (const float*)d_in[6];
  const float* Wo = (const float*)d_in[7];
  const float* bo = (const float*)d_in[8];

  float* outp = (float*)d_out;
  float* attnp = outp + (size_t)4194304;

  unsigned short* Qw = (unsigned short*)d_ws;
  unsigned short* Kw = Qw + (size_t)4194304;
  unsigned short* Vt = Kw + (size_t)4194304;
  unsigned short* Cw = Vt + (size_t)4194304;  // ctx; aliased as xb before attn

  const bool wbf = ws_size >= (size_t)40 * 1024 * 1024;
  dim3 blk(256, 1, 1);

  if (wbf) {
    unsigned short* Wqb = Cw + (size_t)4194304;
    unsigned short* Wkb = Wqb + (size_t)1048576;
    unsigned short* Wvb = Wkb + (size_t)1048576;
    unsigned short* Wob = Wvb + (size_t)1048576;
    cvt_all<<<dim3(4096), blk, 0, stream>>>(x, Wq, Wk, Wv, Wo, Cw, Wqb, Wkb, Wvb, Wob);
    gemm_qkv<1><<<dim3(768), blk, 0, stream>>>(Cw, Wqb, Wkb, Wvb, bq, bk, bv, Qw, Kw, Vt);
    attn_kernel<<<dim3(512), dim3(512), 0, stream>>>(Qw, Kw, Vt, attnp, Cw);
    gemm_o<1><<<dim3(256), blk, 0, stream>>>(Cw, Wob, bo, outp);
  } else {
    cvt_all<<<dim3(2048), blk, 0, stream>>>(x, Wq, Wk, Wv, Wo, Cw, nullptr, nullptr,
                                            nullptr, nullptr);
    gemm_qkv<0><<<dim3(768), blk, 0, stream>>>(Cw, Wq, Wk, Wv, bq, bk, bv, Qw, Kw, Vt);
    attn_kernel<<<dim3(512), dim3(512), 0, stream>>>(Qw, Kw, Vt, attnp, Cw);
    gemm_o<0><<<dim3(256), blk, 0, stream>>>(Cw, Wo, bo, outp);
  }
}